// Round 1
// baseline (37000.656 us; speedup 1.0000x reference)
//
#include <hip/hip_runtime.h>
#include <math.h>

// ---- problem constants ----
#define BB 64
#define CC 3
#define IMG 224
#define PP 16
#define DD 768
#define NH 12
#define NL 12
#define GG 14
#define TT 196
#define HD 64

// ================= fp32 tiled GEMM:  C[M,N] = A[M,K] @ W[N,K]^T + bias  =================
// M % 64 == 0, N % 64 == 0, K % 16 == 0 (all true for this problem)
// MODE 0: plain+bias   MODE 1: bias + exact GELU
template <int MODE>
__global__ __launch_bounds__(256) void gemm_bt(const float* __restrict__ A,
                                               const float* __restrict__ W,
                                               const float* __restrict__ bias,
                                               float* __restrict__ Cmat,
                                               int M, int N, int K) {
    __shared__ float As[16][68];
    __shared__ float Bs[16][68];
    const int nb = N >> 6;
    const int m0 = (blockIdx.x / nb) * 64;
    const int n0 = (blockIdx.x % nb) * 64;
    const int tid = threadIdx.x;
    const int lr = tid >> 2;          // 0..63 row-in-tile for loads
    const int lk = (tid & 3) * 4;     // 0,4,8,12 k-offset for loads
    const int tx = tid & 15, ty = tid >> 4;

    float acc[4][4] = {};
    for (int kt = 0; kt < K; kt += 16) {
        float4 av = *(const float4*)(A + (size_t)(m0 + lr) * K + kt + lk);
        float4 bv = *(const float4*)(W + (size_t)(n0 + lr) * K + kt + lk);
        __syncthreads();
        As[lk + 0][lr] = av.x; As[lk + 1][lr] = av.y; As[lk + 2][lr] = av.z; As[lk + 3][lr] = av.w;
        Bs[lk + 0][lr] = bv.x; Bs[lk + 1][lr] = bv.y; Bs[lk + 2][lr] = bv.z; Bs[lk + 3][lr] = bv.w;
        __syncthreads();
#pragma unroll
        for (int k = 0; k < 16; ++k) {
            float4 a4 = *(const float4*)&As[k][ty * 4];
            float4 b4 = *(const float4*)&Bs[k][tx * 4];
            float a[4] = {a4.x, a4.y, a4.z, a4.w};
            float b[4] = {b4.x, b4.y, b4.z, b4.w};
#pragma unroll
            for (int i = 0; i < 4; ++i)
#pragma unroll
                for (int j = 0; j < 4; ++j) acc[i][j] += a[i] * b[j];
        }
    }
    float4 b4 = *(const float4*)(bias + n0 + tx * 4);
    float bb4[4] = {b4.x, b4.y, b4.z, b4.w};
#pragma unroll
    for (int i = 0; i < 4; ++i) {
        int m = m0 + ty * 4 + i;
        float o[4];
#pragma unroll
        for (int j = 0; j < 4; ++j) {
            float v = acc[i][j] + bb4[j];
            if (MODE == 1) v = 0.5f * v * (1.0f + erff(v * 0.70710678118654752f));
            o[j] = v;
        }
        *(float4*)(Cmat + (size_t)m * N + n0 + tx * 4) = make_float4(o[0], o[1], o[2], o[3]);
    }
}

// ================= patch embedding as im2col GEMM + bias + pos_embed =================
// t[m, d] = sum_k x_im2col[m,k] * patch_w[d,k] + patch_b[d] + pos[m%196, d]
// m = b*196 + gy*14 + gx ; k = c*256 + py*16 + px
__global__ __launch_bounds__(256) void patch_embed_gemm(const float* __restrict__ x,
                                                        const float* __restrict__ W,
                                                        const float* __restrict__ bias,
                                                        const float* __restrict__ pos,
                                                        float* __restrict__ t) {
    __shared__ float As[16][68];
    __shared__ float Bs[16][68];
    const int m0 = (blockIdx.x / 12) * 64;
    const int n0 = (blockIdx.x % 12) * 64;
    const int tid = threadIdx.x;
    const int lr = tid >> 2;
    const int lk = (tid & 3) * 4;
    const int tx = tid & 15, ty = tid >> 4;

    const int m = m0 + lr;
    const int b = m / TT, token = m % TT;
    const int gy = token / GG, gx = token % GG;
    const float* xrow = x + (size_t)b * (CC * IMG * IMG) + (gy * PP) * IMG + gx * PP;

    float acc[4][4] = {};
    for (int kt = 0; kt < 48; ++kt) {  // 48 tiles of 16 over K=768
        int c = kt >> 4, py = kt & 15;
        float4 av = *(const float4*)(xrow + ((size_t)c * IMG + py) * IMG + lk);
        float4 bv = *(const float4*)(W + (size_t)(n0 + lr) * DD + kt * 16 + lk);
        __syncthreads();
        As[lk + 0][lr] = av.x; As[lk + 1][lr] = av.y; As[lk + 2][lr] = av.z; As[lk + 3][lr] = av.w;
        Bs[lk + 0][lr] = bv.x; Bs[lk + 1][lr] = bv.y; Bs[lk + 2][lr] = bv.z; Bs[lk + 3][lr] = bv.w;
        __syncthreads();
#pragma unroll
        for (int k = 0; k < 16; ++k) {
            float4 a4 = *(const float4*)&As[k][ty * 4];
            float4 b4 = *(const float4*)&Bs[k][tx * 4];
            float a[4] = {a4.x, a4.y, a4.z, a4.w};
            float b2[4] = {b4.x, b4.y, b4.z, b4.w};
#pragma unroll
            for (int i = 0; i < 4; ++i)
#pragma unroll
                for (int j = 0; j < 4; ++j) acc[i][j] += a[i] * b2[j];
        }
    }
    float4 bi = *(const float4*)(bias + n0 + tx * 4);
#pragma unroll
    for (int i = 0; i < 4; ++i) {
        int mi = m0 + ty * 4 + i;
        int tok = mi % TT;
        float4 p4 = *(const float4*)(pos + (size_t)tok * DD + n0 + tx * 4);
        float4 o;
        o.x = acc[i][0] + bi.x + p4.x;
        o.y = acc[i][1] + bi.y + p4.y;
        o.z = acc[i][2] + bi.z + p4.z;
        o.w = acc[i][3] + bi.w + p4.w;
        *(float4*)(t + (size_t)mi * DD + n0 + tx * 4) = o;
    }
}

// ================= gather visible tokens (stable True-first order), zero-pad =================
// mask dtype auto-detect: int32 (0/1) vs uint8 (0/1) vs float32 (0.0/1.0)
__global__ __launch_bounds__(256) void gather_kernel(const float* __restrict__ t,
                                                     const unsigned char* __restrict__ mask8,
                                                     float* __restrict__ ctx,
                                                     float* __restrict__ pad_out,
                                                     int* __restrict__ lengths, int Sc) {
    __shared__ int s_order[TT];
    __shared__ int s_len;
    const int b = blockIdx.x, tid = threadIdx.x;
    if (tid == 0) {
        const unsigned int* w = (const unsigned int*)mask8;
        int mode = 0;  // 0=int32, 1=uint8, 2=float32
        bool any_f = false, any_big = false;
        for (int i = 0; i < 64; ++i) {  // first 256 bytes, valid under every interpretation
            unsigned int v = w[i];
            if (v == 0x3F800000u) any_f = true;
            else if (v > 1u) any_big = true;
        }
        if (any_f) mode = 2;
        else if (any_big) mode = 1;
        int cnt = 0;
        for (int i = 0; i < TT; ++i) {
            int mv;
            if (mode == 0) mv = mask8[4 * (b * TT + i)];
            else if (mode == 1) mv = mask8[b * TT + i];
            else mv = (w[b * TT + i] != 0u);
            if (mv) s_order[cnt++] = i;
        }
        s_len = cnt;
        lengths[b] = cnt;
    }
    __syncthreads();
    const int len = s_len;
    for (int idx = tid; idx < Sc * DD; idx += 256) {
        int s = idx / DD, d = idx - s * DD;
        float v = 0.f;
        if (s < len) v = t[((size_t)b * TT + s_order[s]) * DD + d];
        ctx[((size_t)b * Sc + s) * DD + d] = v;
    }
    for (int s = tid; s < Sc; s += 256) pad_out[b * Sc + s] = (s < len) ? 0.f : 1.f;
}

// ================= attention: one block per (b, head); online softmax, pad keys skipped =================
__global__ __launch_bounds__(256) void attn_kernel(const float* __restrict__ qkv,
                                                   const int* __restrict__ lengths,
                                                   float* __restrict__ outp, int Sc) {
    extern __shared__ float smem[];
    float* Ks = smem;
    float* Vs = smem + (size_t)Sc * HD;
    const int b = blockIdx.x / NH, h = blockIdx.x % NH;
    const int len = lengths[b];
    const int tid = threadIdx.x;
    const float* base = qkv + ((size_t)b * Sc) * (3 * DD) + h * HD;
    for (int idx = tid; idx < Sc * HD; idx += 256) {
        int s = idx >> 6, d = idx & 63;
        Ks[idx] = base[(size_t)s * (3 * DD) + DD + d];
        Vs[idx] = base[(size_t)s * (3 * DD) + 2 * DD + d];
    }
    __syncthreads();
    const int wave = tid >> 6, lane = tid & 63;
    for (int q = wave; q < Sc; q += 4) {
        float qv = base[(size_t)q * (3 * DD) + lane];
        float m = -1e30f, l = 0.f, acc = 0.f;
        for (int j = 0; j < len; ++j) {
            float s = qv * Ks[j * HD + lane];
#pragma unroll
            for (int off = 32; off; off >>= 1) s += __shfl_xor(s, off, 64);
            s *= 0.125f;  // 1/sqrt(64)
            float mn = fmaxf(m, s);
            float scale = __expf(m - mn);
            float p = __expf(s - mn);
            l = l * scale + p;
            acc = acc * scale + p * Vs[j * HD + lane];
            m = mn;
        }
        outp[((size_t)(b * Sc + q)) * DD + h * HD + lane] = acc / l;
    }
}

// ================= layernorm (optional residual add), D=768, one block per row =================
__global__ __launch_bounds__(256) void ln_kernel(const float* x, const float* yadd,
                                                 const float* __restrict__ g,
                                                 const float* __restrict__ beta,
                                                 float* outp) {
    __shared__ float red[4];
    const size_t row = blockIdx.x;
    const int tid = threadIdx.x;
    float v[3];
#pragma unroll
    for (int i = 0; i < 3; ++i) {
        int d = tid + i * 256;
        float t0 = x[row * DD + d];
        if (yadd) t0 += yadd[row * DD + d];
        v[i] = t0;
    }
    float s = v[0] + v[1] + v[2];
#pragma unroll
    for (int off = 32; off; off >>= 1) s += __shfl_xor(s, off, 64);
    if ((tid & 63) == 0) red[tid >> 6] = s;
    __syncthreads();
    float mean = (red[0] + red[1] + red[2] + red[3]) * (1.0f / 768.0f);
    __syncthreads();
    float vs = 0.f;
#pragma unroll
    for (int i = 0; i < 3; ++i) { float d0 = v[i] - mean; vs += d0 * d0; }
#pragma unroll
    for (int off = 32; off; off >>= 1) vs += __shfl_xor(vs, off, 64);
    if ((tid & 63) == 0) red[tid >> 6] = vs;
    __syncthreads();
    float var = (red[0] + red[1] + red[2] + red[3]) * (1.0f / 768.0f);
    float inv = rsqrtf(var + 1e-5f);
#pragma unroll
    for (int i = 0; i < 3; ++i) {
        int d = tid + i * 256;
        outp[row * DD + d] = (v[i] - mean) * inv * g[d] + beta[d];
    }
}

extern "C" void kernel_launch(void* const* d_in, const int* in_sizes, int n_in,
                              void* d_out, int out_size, void* d_ws, size_t ws_size,
                              hipStream_t stream) {
    (void)in_sizes; (void)n_in; (void)ws_size;
    const float* x          = (const float*)d_in[0];
    const unsigned char* mk = (const unsigned char*)d_in[1];
    const float* patch_w    = (const float*)d_in[2];
    const float* patch_b    = (const float*)d_in[3];
    const float* pos        = (const float*)d_in[4];
    const float* in_proj_w  = (const float*)d_in[5];
    const float* in_proj_b  = (const float*)d_in[6];
    const float* out_w      = (const float*)d_in[7];
    const float* out_b      = (const float*)d_in[8];
    const float* ln1_g      = (const float*)d_in[9];
    const float* ln1_b      = (const float*)d_in[10];
    const float* ffn_w1     = (const float*)d_in[11];
    const float* ffn_b1     = (const float*)d_in[12];
    const float* ffn_w2     = (const float*)d_in[13];
    const float* ffn_b2     = (const float*)d_in[14];
    const float* ln2_g      = (const float*)d_in[15];
    const float* ln2_b      = (const float*)d_in[16];
    const float* norm_g     = (const float*)d_in[17];
    const float* norm_b     = (const float*)d_in[18];
    float* out = (float*)d_out;

    const int Sc = out_size / (BB * (DD + 1));   // out = B*Sc*D + B*Sc
    const size_t M = (size_t)BB * Sc;

    // workspace layout (floats)
    float* ws = (float*)d_ws;
    size_t bufA_elems = (size_t)BB * TT * DD;            // patch-embed output t
    if (M * 4 * DD > bufA_elems) bufA_elems = M * 4 * DD; // also holds qkv (3D) / ffn hidden (4D)
    float* bufA = ws;                    // t, then qkv, then ffn hidden
    float* bufB = bufA + M * 3 * DD;     // attn out — aliases the unused top of bufA (qkv uses only 3D of 4D)
    float* bufC = bufA + bufA_elems;     // proj / ffn2 output (pre-LN)
    float* ctx  = bufC + M * DD;         // running activations
    int* lengths = (int*)(ctx + M * DD);

    // 1) patch embedding (+bias +pos) -> t
    patch_embed_gemm<<<TT * 12, 256, 0, stream>>>(x, patch_w, patch_b, pos, bufA);
    // 2) gather visible tokens -> ctx ; write pad-mask output + lengths
    gather_kernel<<<BB, 256, 0, stream>>>(bufA, mk, ctx, out + M * DD, lengths, Sc);

    size_t smem = (size_t)Sc * HD * 2 * sizeof(float);
    if (smem > 65536) {
        (void)hipFuncSetAttribute((const void*)attn_kernel,
                                  hipFuncAttributeMaxDynamicSharedMemorySize, (int)smem);
    }

    for (int l = 0; l < NL; ++l) {
        // qkv = ctx @ Wqkv^T + b   [M, 2304]
        gemm_bt<0><<<Sc * 36, 256, 0, stream>>>(ctx, in_proj_w + (size_t)l * 3 * DD * DD,
                                                in_proj_b + (size_t)l * 3 * DD, bufA,
                                                (int)M, 3 * DD, DD);
        // attention -> bufB [M, 768]
        attn_kernel<<<BB * NH, 256, smem, stream>>>(bufA, lengths, bufB, Sc);
        // proj -> bufC
        gemm_bt<0><<<Sc * 12, 256, 0, stream>>>(bufB, out_w + (size_t)l * DD * DD,
                                                out_b + (size_t)l * DD, bufC,
                                                (int)M, DD, DD);
        // ctx = LN(ctx + bufC)
        ln_kernel<<<(int)M, 256, 0, stream>>>(ctx, bufC, ln1_g + (size_t)l * DD,
                                              ln1_b + (size_t)l * DD, ctx);
        // h = gelu(ctx @ W1^T + b1)  [M, 3072]
        gemm_bt<1><<<Sc * 48, 256, 0, stream>>>(ctx, ffn_w1 + (size_t)l * 4 * DD * DD,
                                                ffn_b1 + (size_t)l * 4 * DD, bufA,
                                                (int)M, 4 * DD, DD);
        // ffn2 -> bufC
        gemm_bt<0><<<Sc * 12, 256, 0, stream>>>(bufA, ffn_w2 + (size_t)l * 4 * DD * DD,
                                                ffn_b2 + (size_t)l * DD, bufC,
                                                (int)M, DD, 4 * DD);
        // ctx = LN(ctx + bufC)
        ln_kernel<<<(int)M, 256, 0, stream>>>(ctx, bufC, ln2_g + (size_t)l * DD,
                                              ln2_b + (size_t)l * DD, ctx);
    }
    // final LN -> out
    ln_kernel<<<(int)M, 256, 0, stream>>>(ctx, nullptr, norm_g, norm_b, out);
}

// Round 2
// 8011.705 us; speedup vs baseline: 4.6183x; 4.6183x over previous
//
#include <hip/hip_runtime.h>
#include <math.h>

// ---- problem constants ----
#define BB 64
#define IMG 224
#define PP 16
#define DD 768
#define NH 12
#define NL 12
#define GG 14
#define TT 196
#define HD 64

typedef __attribute__((ext_vector_type(8))) short short8;
typedef __attribute__((ext_vector_type(4))) float floatx4;

__device__ __forceinline__ unsigned short f2bfu(float f) {
    union { float f; unsigned int u; } v; v.f = f;
    unsigned int r = v.u + 0x7FFFu + ((v.u >> 16) & 1u);   // RNE
    return (unsigned short)(r >> 16);
}

__device__ __forceinline__ void g2lds16(const void* g, void* l) {
    __builtin_amdgcn_global_load_lds(
        (const __attribute__((address_space(1))) unsigned int*)g,
        (__attribute__((address_space(3))) unsigned int*)l, 16, 0, 0);
}

// ================= bf16 MFMA GEMM:  C[M,N] = A[M,K] @ W[N,K]^T + bias =================
// 128x128 tile, BK=32, 4 waves each computing 64x64 via 4x4 MFMA 16x16x32 tiles.
// MODE 0: fp32 out + bias.  MODE 1: bias + exact GELU, bf16 out.
template <int MODE>
__global__ __launch_bounds__(256) void gemm_mfma(const unsigned short* __restrict__ A,
                                                 const unsigned short* __restrict__ W,
                                                 const float* __restrict__ bias,
                                                 float* __restrict__ Cf,
                                                 unsigned short* __restrict__ Cb,
                                                 int M, int N, int K) {
    __shared__ unsigned short As[128 * 32];
    __shared__ unsigned short Bs[128 * 32];
    const int nb = N >> 7;
    const int m0 = (blockIdx.x / nb) << 7;
    const int n0 = (blockIdx.x % nb) << 7;
    const int tid = threadIdx.x;
    const int lane = tid & 63;
    const int wave = tid >> 6;
    const int wm = (wave >> 1) << 6;
    const int wn = (wave & 1) << 6;
    const int fr = lane & 15;          // frag row (A) / col (B)
    const int fk = (lane >> 4) << 3;   // frag k offset (0 or 8..24 halves)

    const unsigned short* Ag = A + (size_t)(m0 + (tid >> 2)) * K + (tid & 3) * 8;
    const unsigned short* Wg = W + (size_t)(n0 + (tid >> 2)) * K + (tid & 3) * 8;
    unsigned short* lA = As + tid * 8;   // lds byte addr = tid*16 (wave-uniform base + lane*16)
    unsigned short* lB = Bs + tid * 8;
    const size_t rowskip = (size_t)64 * K;

    floatx4 acc[4][4];
#pragma unroll
    for (int i = 0; i < 4; ++i)
#pragma unroll
        for (int j = 0; j < 4; ++j) acc[i][j] = (floatx4){0.f, 0.f, 0.f, 0.f};

    for (int kt = 0; kt < K; kt += 32) {
        g2lds16(Ag + kt, lA);
        g2lds16(Ag + kt + rowskip, lA + 64 * 32);
        g2lds16(Wg + kt, lB);
        g2lds16(Wg + kt + rowskip, lB + 64 * 32);
        __syncthreads();   // drains vmcnt before barrier (compiler-inserted)
        short8 af[4], bf[4];
#pragma unroll
        for (int i = 0; i < 4; ++i) {
            af[i] = *(const short8*)(As + (wm + i * 16 + fr) * 32 + fk);
            bf[i] = *(const short8*)(Bs + (wn + i * 16 + fr) * 32 + fk);
        }
#pragma unroll
        for (int i = 0; i < 4; ++i)
#pragma unroll
            for (int j = 0; j < 4; ++j)
                acc[i][j] = __builtin_amdgcn_mfma_f32_16x16x32_bf16(af[i], bf[j], acc[i][j], 0, 0, 0);
        __syncthreads();   // protect LDS before next stage
    }

    const int r0 = (lane >> 4) << 2;   // C/D: row=(lane>>4)*4+reg, col=lane&15 (m89-verified)
#pragma unroll
    for (int j = 0; j < 4; ++j) {
        const int col = n0 + wn + j * 16 + fr;
        const float bv = bias[col];
#pragma unroll
        for (int i = 0; i < 4; ++i) {
            const int row = m0 + wm + i * 16 + r0;
#pragma unroll
            for (int r = 0; r < 4; ++r) {
                float v = acc[i][j][r] + bv;
                if (MODE == 1) {
                    v = 0.5f * v * (1.0f + erff(v * 0.70710678118654752f));
                    Cb[(size_t)(row + r) * N + col] = f2bfu(v);
                } else {
                    Cf[(size_t)(row + r) * N + col] = v;
                }
            }
        }
    }
}

// ================= patch embedding as im2col fp32 GEMM + bias + pos_embed =================
__global__ __launch_bounds__(256) void patch_embed_gemm(const float* __restrict__ x,
                                                        const float* __restrict__ W,
                                                        const float* __restrict__ bias,
                                                        const float* __restrict__ pos,
                                                        float* __restrict__ t) {
    __shared__ float Asm[16][68];
    __shared__ float Bsm[16][68];
    const int m0 = (blockIdx.x / 12) * 64;
    const int n0 = (blockIdx.x % 12) * 64;
    const int tid = threadIdx.x;
    const int lr = tid >> 2;
    const int lk = (tid & 3) * 4;
    const int tx = tid & 15, ty = tid >> 4;

    const int m = m0 + lr;
    const int b = m / TT, token = m % TT;
    const int gy = token / GG, gx = token % GG;
    const float* xrow = x + (size_t)b * (3 * IMG * IMG) + (gy * PP) * IMG + gx * PP;

    float acc[4][4] = {};
    for (int kt = 0; kt < 48; ++kt) {
        int c = kt >> 4, py = kt & 15;
        float4 av = *(const float4*)(xrow + ((size_t)c * IMG + py) * IMG + lk);
        float4 bv = *(const float4*)(W + (size_t)(n0 + lr) * DD + kt * 16 + lk);
        __syncthreads();
        Asm[lk + 0][lr] = av.x; Asm[lk + 1][lr] = av.y; Asm[lk + 2][lr] = av.z; Asm[lk + 3][lr] = av.w;
        Bsm[lk + 0][lr] = bv.x; Bsm[lk + 1][lr] = bv.y; Bsm[lk + 2][lr] = bv.z; Bsm[lk + 3][lr] = bv.w;
        __syncthreads();
#pragma unroll
        for (int k = 0; k < 16; ++k) {
            float4 a4 = *(const float4*)&Asm[k][ty * 4];
            float4 b4 = *(const float4*)&Bsm[k][tx * 4];
            float a[4] = {a4.x, a4.y, a4.z, a4.w};
            float b2[4] = {b4.x, b4.y, b4.z, b4.w};
#pragma unroll
            for (int i = 0; i < 4; ++i)
#pragma unroll
                for (int j = 0; j < 4; ++j) acc[i][j] += a[i] * b2[j];
        }
    }
    float4 bi = *(const float4*)(bias + n0 + tx * 4);
#pragma unroll
    for (int i = 0; i < 4; ++i) {
        int mi = m0 + ty * 4 + i;
        int tok = mi % TT;
        float4 p4 = *(const float4*)(pos + (size_t)tok * DD + n0 + tx * 4);
        float4 o;
        o.x = acc[i][0] + bi.x + p4.x;
        o.y = acc[i][1] + bi.y + p4.y;
        o.z = acc[i][2] + bi.z + p4.z;
        o.w = acc[i][3] + bi.w + p4.w;
        *(float4*)(t + (size_t)mi * DD + n0 + tx * 4) = o;
    }
}

// ================= gather visible tokens; write fp32 ctx + bf16 ctx + pad mask =================
__global__ __launch_bounds__(256) void gather_kernel(const float* __restrict__ t,
                                                     const unsigned char* __restrict__ mask8,
                                                     float* __restrict__ ctx,
                                                     unsigned short* __restrict__ ctxb,
                                                     float* __restrict__ pad_out,
                                                     int* __restrict__ lengths, int Sc) {
    __shared__ int s_order[TT];
    __shared__ int s_len;
    const int b = blockIdx.x, tid = threadIdx.x;
    if (tid == 0) {
        const unsigned int* w = (const unsigned int*)mask8;
        int mode = 0;  // 0=int32, 1=uint8, 2=float32
        bool any_f = false, any_big = false;
        for (int i = 0; i < 64; ++i) {
            unsigned int v = w[i];
            if (v == 0x3F800000u) any_f = true;
            else if (v > 1u) any_big = true;
        }
        if (any_f) mode = 2;
        else if (any_big) mode = 1;
        int cnt = 0;
        for (int i = 0; i < TT; ++i) {
            int mv;
            if (mode == 0) mv = mask8[4 * (b * TT + i)];
            else if (mode == 1) mv = mask8[b * TT + i];
            else mv = (w[b * TT + i] != 0u);
            if (mv) s_order[cnt++] = i;
        }
        s_len = cnt;
        lengths[b] = cnt;
    }
    __syncthreads();
    const int len = s_len;
    for (int idx = tid; idx < Sc * DD; idx += 256) {
        int s = idx / DD, d = idx - s * DD;
        float v = 0.f;
        if (s < len) v = t[((size_t)b * TT + s_order[s]) * DD + d];
        ctx[((size_t)b * Sc + s) * DD + d] = v;
        ctxb[((size_t)b * Sc + s) * DD + d] = f2bfu(v);
    }
    for (int s = tid; s < Sc; s += 256) pad_out[b * Sc + s] = (s < len) ? 0.f : 1.f;
}

// ================= attention v2: block per (b,h); transposed-K LDS; wave per query =================
template <int P>   // P = ceil(Sc/64)
__global__ __launch_bounds__(256) void attn_t(const float* __restrict__ qkv,
                                              const int* __restrict__ lengths,
                                              unsigned short* __restrict__ outp, int Sc) {
    constexpr int KtSp = P * 64 + 1;   // odd stride -> conflict-free transpose writes
    extern __shared__ float smem[];
    float* Kt = smem;                  // [64][KtSp]
    float* Vs = smem + 64 * KtSp;      // [Sc][64]
    const int b = blockIdx.x / NH, h = blockIdx.x % NH;
    const int len = lengths[b];
    const int tid = threadIdx.x;
    const float* base = qkv + (size_t)b * Sc * (3 * DD) + h * HD;
    for (int idx = tid; idx < Sc * HD; idx += 256) {
        int s = idx >> 6, d = idx & 63;
        Kt[d * KtSp + s] = base[(size_t)s * (3 * DD) + DD + d];
        Vs[idx] = base[(size_t)s * (3 * DD) + 2 * DD + d];
    }
    __syncthreads();
    const int wave = tid >> 6, lane = tid & 63;
    for (int q = wave; q < Sc; q += 4) {
        const float qv = base[(size_t)q * (3 * DD) + lane];
        float s0 = 0.f, s1 = 0.f, s2 = 0.f, s3 = 0.f;
#pragma unroll
        for (int d = 0; d < 64; ++d) {
            const float qd = __shfl(qv, d, 64);
            const float* kr = Kt + d * KtSp + lane;
            s0 += qd * kr[0];
            if (P > 1) s1 += qd * kr[64];
            if (P > 2) s2 += qd * kr[128];
            if (P > 3) s3 += qd * kr[192];
        }
        s0 = (lane < len) ? s0 * 0.125f : -1e30f;
        if (P > 1) s1 = (64 + lane < len) ? s1 * 0.125f : -1e30f;
        if (P > 2) s2 = (128 + lane < len) ? s2 * 0.125f : -1e30f;
        if (P > 3) s3 = (192 + lane < len) ? s3 * 0.125f : -1e30f;
        float m = s0;
        if (P > 1) m = fmaxf(m, s1);
        if (P > 2) m = fmaxf(m, s2);
        if (P > 3) m = fmaxf(m, s3);
#pragma unroll
        for (int off = 32; off; off >>= 1) m = fmaxf(m, __shfl_xor(m, off, 64));
        s0 = __expf(s0 - m);
        if (P > 1) s1 = __expf(s1 - m);
        if (P > 2) s2 = __expf(s2 - m);
        if (P > 3) s3 = __expf(s3 - m);
        float l = s0;
        if (P > 1) l += s1;
        if (P > 2) l += s2;
        if (P > 3) l += s3;
#pragma unroll
        for (int off = 32; off; off >>= 1) l += __shfl_xor(l, off, 64);
        float acc = 0.f;
        {
            int c = len < 64 ? len : 64;
#pragma unroll 4
            for (int j = 0; j < c; ++j) acc += __shfl(s0, j, 64) * Vs[j * 64 + lane];
        }
        if (P > 1 && len > 64) {
            int c = len - 64; if (c > 64) c = 64;
#pragma unroll 4
            for (int j = 0; j < c; ++j) acc += __shfl(s1, j, 64) * Vs[(64 + j) * 64 + lane];
        }
        if (P > 2 && len > 128) {
            int c = len - 128; if (c > 64) c = 64;
#pragma unroll 4
            for (int j = 0; j < c; ++j) acc += __shfl(s2, j, 64) * Vs[(128 + j) * 64 + lane];
        }
        if (P > 3 && len > 192) {
            int c = len - 192; if (c > 64) c = 64;
#pragma unroll 4
            for (int j = 0; j < c; ++j) acc += __shfl(s3, j, 64) * Vs[(192 + j) * 64 + lane];
        }
        outp[((size_t)b * Sc + q) * DD + h * HD + lane] = f2bfu(acc / l);
    }
}

// ================= layernorm (+optional residual), fp32 out + optional bf16 out =================
__global__ __launch_bounds__(256) void ln_kernel(const float* __restrict__ x,
                                                 const float* __restrict__ yadd,
                                                 const float* __restrict__ g,
                                                 const float* __restrict__ beta,
                                                 float* __restrict__ outf,
                                                 unsigned short* __restrict__ outb) {
    __shared__ float red[4];
    const size_t row = blockIdx.x;
    const int tid = threadIdx.x;
    float v[3];
#pragma unroll
    for (int i = 0; i < 3; ++i) {
        int d = tid + i * 256;
        float t0 = x[row * DD + d];
        if (yadd) t0 += yadd[row * DD + d];
        v[i] = t0;
    }
    float s = v[0] + v[1] + v[2];
#pragma unroll
    for (int off = 32; off; off >>= 1) s += __shfl_xor(s, off, 64);
    if ((tid & 63) == 0) red[tid >> 6] = s;
    __syncthreads();
    float mean = (red[0] + red[1] + red[2] + red[3]) * (1.0f / 768.0f);
    __syncthreads();
    float vs = 0.f;
#pragma unroll
    for (int i = 0; i < 3; ++i) { float d0 = v[i] - mean; vs += d0 * d0; }
#pragma unroll
    for (int off = 32; off; off >>= 1) vs += __shfl_xor(vs, off, 64);
    if ((tid & 63) == 0) red[tid >> 6] = vs;
    __syncthreads();
    float var = (red[0] + red[1] + red[2] + red[3]) * (1.0f / 768.0f);
    float inv = rsqrtf(var + 1e-5f);
#pragma unroll
    for (int i = 0; i < 3; ++i) {
        int d = tid + i * 256;
        float o = (v[i] - mean) * inv * g[d] + beta[d];
        outf[row * DD + d] = o;
        if (outb) outb[row * DD + d] = f2bfu(o);
    }
}

// ================= fp32 -> bf16 conversion of one layer's 4 weight mats (contiguous dst) ====
__global__ __launch_bounds__(256) void convert4_bf16(const float* __restrict__ a, int na,
                                                     const float* __restrict__ b, int nb,
                                                     const float* __restrict__ c, int nc,
                                                     const float* __restrict__ d, int nd,
                                                     unsigned short* __restrict__ dst) {
    const int total4 = (na + nb + nc + nd) >> 2;
    for (int u = blockIdx.x * 256 + threadIdx.x; u < total4; u += gridDim.x * 256) {
        int e = u << 2;
        const float* src; int off;
        if (e < na) { src = a; off = e; }
        else if (e < na + nb) { src = b; off = e - na; }
        else if (e < na + nb + nc) { src = c; off = e - na - nb; }
        else { src = d; off = e - na - nb - nc; }
        float4 v = *(const float4*)(src + off);
        ushort4 o;
        o.x = f2bfu(v.x); o.y = f2bfu(v.y); o.z = f2bfu(v.z); o.w = f2bfu(v.w);
        *(ushort4*)(dst + e) = o;
    }
}

extern "C" void kernel_launch(void* const* d_in, const int* in_sizes, int n_in,
                              void* d_out, int out_size, void* d_ws, size_t ws_size,
                              hipStream_t stream) {
    (void)in_sizes; (void)n_in; (void)ws_size;
    const float* x          = (const float*)d_in[0];
    const unsigned char* mk = (const unsigned char*)d_in[1];
    const float* patch_w    = (const float*)d_in[2];
    const float* patch_b    = (const float*)d_in[3];
    const float* pos        = (const float*)d_in[4];
    const float* in_proj_w  = (const float*)d_in[5];
    const float* in_proj_b  = (const float*)d_in[6];
    const float* out_w      = (const float*)d_in[7];
    const float* out_b      = (const float*)d_in[8];
    const float* ln1_g      = (const float*)d_in[9];
    const float* ln1_b      = (const float*)d_in[10];
    const float* ffn_w1     = (const float*)d_in[11];
    const float* ffn_b1     = (const float*)d_in[12];
    const float* ffn_w2     = (const float*)d_in[13];
    const float* ffn_b2     = (const float*)d_in[14];
    const float* ln2_g      = (const float*)d_in[15];
    const float* ln2_b      = (const float*)d_in[16];
    const float* norm_g     = (const float*)d_in[17];
    const float* norm_b     = (const float*)d_in[18];
    float* out = (float*)d_out;

    const int Sc = out_size / (BB * (DD + 1));
    const int M = BB * Sc;
    const int Mp = ((M + 127) / 128) * 128;
    const int MB = Mp / 128;

    // ---- workspace layout ----
    float* t_f   = (float*)d_ws;                          // B*T*D
    float* qkv_f = t_f + (size_t)BB * TT * DD;            // Mp*2304
    float* ctx_f = qkv_f + (size_t)Mp * 2304;             // Mp*768
    float* y_f   = ctx_f + (size_t)Mp * DD;               // Mp*768
    unsigned short* ctx_b  = (unsigned short*)(y_f + (size_t)Mp * DD);  // Mp*768
    unsigned short* attn_b = ctx_b + (size_t)Mp * DD;                    // Mp*768
    unsigned short* h_b    = attn_b + (size_t)Mp * DD;                   // Mp*3072
    unsigned short* wq     = h_b + (size_t)Mp * 4 * DD;                  // 2304*768
    unsigned short* wo     = wq + (size_t)3 * DD * DD;                   // 768*768
    unsigned short* w1     = wo + (size_t)DD * DD;                       // 3072*768
    unsigned short* w2     = w1 + (size_t)4 * DD * DD;                   // 768*3072
    int* lengths = (int*)(w2 + (size_t)4 * DD * DD);

    // 1) patch embedding (+bias +pos) -> t
    patch_embed_gemm<<<TT * 12, 256, 0, stream>>>(x, patch_w, patch_b, pos, t_f);
    // 2) gather visible tokens -> ctx fp32 + bf16; write pad-mask output + lengths
    gather_kernel<<<BB, 256, 0, stream>>>(t_f, mk, ctx_f, ctx_b, out + (size_t)M * DD, lengths, Sc);

    int P = (Sc + 63) / 64; if (P > 4) P = 4;
    size_t smem_attn = (size_t)(64 * (P * 64 + 1) + Sc * 64) * sizeof(float);
    if (smem_attn > 65536) {
        const void* fp = (P == 1) ? (const void*)attn_t<1> : (P == 2) ? (const void*)attn_t<2>
                       : (P == 3) ? (const void*)attn_t<3> : (const void*)attn_t<4>;
        (void)hipFuncSetAttribute(fp, hipFuncAttributeMaxDynamicSharedMemorySize, (int)smem_attn);
    }

    for (int l = 0; l < NL; ++l) {
        // convert this layer's weights to bf16 (contiguous wq|wo|w1|w2)
        convert4_bf16<<<1024, 256, 0, stream>>>(
            in_proj_w + (size_t)l * 3 * DD * DD, 3 * DD * DD,
            out_w + (size_t)l * DD * DD, DD * DD,
            ffn_w1 + (size_t)l * 4 * DD * DD, 4 * DD * DD,
            ffn_w2 + (size_t)l * 4 * DD * DD, 4 * DD * DD, wq);
        // qkv = ctx @ Wqkv^T + b   [Mp, 2304] fp32
        gemm_mfma<0><<<MB * 18, 256, 0, stream>>>(ctx_b, wq, in_proj_b + (size_t)l * 3 * DD,
                                                  qkv_f, nullptr, Mp, 3 * DD, DD);
        // attention -> attn_b (bf16)
        switch (P) {
            case 1: attn_t<1><<<BB * NH, 256, smem_attn, stream>>>(qkv_f, lengths, attn_b, Sc); break;
            case 2: attn_t<2><<<BB * NH, 256, smem_attn, stream>>>(qkv_f, lengths, attn_b, Sc); break;
            case 3: attn_t<3><<<BB * NH, 256, smem_attn, stream>>>(qkv_f, lengths, attn_b, Sc); break;
            default: attn_t<4><<<BB * NH, 256, smem_attn, stream>>>(qkv_f, lengths, attn_b, Sc); break;
        }
        // proj -> y_f fp32
        gemm_mfma<0><<<MB * 6, 256, 0, stream>>>(attn_b, wo, out_b + (size_t)l * DD,
                                                 y_f, nullptr, Mp, DD, DD);
        // ctx = LN(ctx + y) -> fp32 + bf16
        ln_kernel<<<M, 256, 0, stream>>>(ctx_f, y_f, ln1_g + (size_t)l * DD,
                                         ln1_b + (size_t)l * DD, ctx_f, ctx_b);
        // h = gelu(ctx @ W1^T + b1) -> bf16 [Mp, 3072]
        gemm_mfma<1><<<MB * 24, 256, 0, stream>>>(ctx_b, w1, ffn_b1 + (size_t)l * 4 * DD,
                                                  nullptr, h_b, Mp, 4 * DD, DD);
        // ffn2 -> y_f fp32
        gemm_mfma<0><<<MB * 6, 256, 0, stream>>>(h_b, w2, ffn_b2 + (size_t)l * DD,
                                                 y_f, nullptr, Mp, DD, 4 * DD);
        // ctx = LN(ctx + y) -> fp32 + bf16
        ln_kernel<<<M, 256, 0, stream>>>(ctx_f, y_f, ln2_g + (size_t)l * DD,
                                         ln2_b + (size_t)l * DD, ctx_f, ctx_b);
    }
    // final LN -> out (fp32 only)
    ln_kernel<<<M, 256, 0, stream>>>(ctx_f, nullptr, norm_g, norm_b, out, nullptr);
}

// Round 3
// 5314.981 us; speedup vs baseline: 6.9616x; 1.5074x over previous
//
#include <hip/hip_runtime.h>
#include <math.h>

// ---- problem constants ----
#define BB 64
#define IMG 224
#define PP 16
#define DD 768
#define NH 12
#define NL 12
#define GG 14
#define TT 196
#define HD 64

typedef __attribute__((ext_vector_type(8))) short short8;
typedef __attribute__((ext_vector_type(4))) float floatx4;

__device__ __forceinline__ unsigned short f2bfu(float f) {
    union { float f; unsigned int u; } v; v.f = f;
    unsigned int r = v.u + 0x7FFFu + ((v.u >> 16) & 1u);   // RNE
    return (unsigned short)(r >> 16);
}

__device__ __forceinline__ void g2lds16(const void* g, void* l) {
    __builtin_amdgcn_global_load_lds(
        (const __attribute__((address_space(1))) unsigned int*)g,
        (__attribute__((address_space(3))) unsigned int*)l, 16, 0, 0);
}

// ================= bf16 MFMA GEMM:  C[M,N] = A[M,K] @ W[N,K]^T + bias =================
// 128x128 tile, BK=32, 4 waves each computing 64x64 via 4x4 MFMA 16x16x32 tiles.
// MODE 0: fp32 out + bias.  MODE 1: bias + exact GELU, bf16 out.
template <int MODE>
__global__ __launch_bounds__(256) void gemm_mfma(const unsigned short* __restrict__ A,
                                                 const unsigned short* __restrict__ W,
                                                 const float* __restrict__ bias,
                                                 float* __restrict__ Cf,
                                                 unsigned short* __restrict__ Cb,
                                                 int M, int N, int K) {
    __shared__ unsigned short As[128 * 32];
    __shared__ unsigned short Bs[128 * 32];
    const int nb = N >> 7;
    const int m0 = (blockIdx.x / nb) << 7;
    const int n0 = (blockIdx.x % nb) << 7;
    const int tid = threadIdx.x;
    const int lane = tid & 63;
    const int wave = tid >> 6;
    const int wm = (wave >> 1) << 6;
    const int wn = (wave & 1) << 6;
    const int fr = lane & 15;          // frag row (A) / col (B)
    const int fk = (lane >> 4) << 3;   // frag k offset

    const unsigned short* Ag = A + (size_t)(m0 + (tid >> 2)) * K + (tid & 3) * 8;
    const unsigned short* Wg = W + (size_t)(n0 + (tid >> 2)) * K + (tid & 3) * 8;
    unsigned short* lA = As + tid * 8;
    unsigned short* lB = Bs + tid * 8;
    const size_t rowskip = (size_t)64 * K;

    floatx4 acc[4][4];
#pragma unroll
    for (int i = 0; i < 4; ++i)
#pragma unroll
        for (int j = 0; j < 4; ++j) acc[i][j] = (floatx4){0.f, 0.f, 0.f, 0.f};

    for (int kt = 0; kt < K; kt += 32) {
        g2lds16(Ag + kt, lA);
        g2lds16(Ag + kt + rowskip, lA + 64 * 32);
        g2lds16(Wg + kt, lB);
        g2lds16(Wg + kt + rowskip, lB + 64 * 32);
        __syncthreads();
        short8 af[4], bf[4];
#pragma unroll
        for (int i = 0; i < 4; ++i) {
            af[i] = *(const short8*)(As + (wm + i * 16 + fr) * 32 + fk);
            bf[i] = *(const short8*)(Bs + (wn + i * 16 + fr) * 32 + fk);
        }
#pragma unroll
        for (int i = 0; i < 4; ++i)
#pragma unroll
            for (int j = 0; j < 4; ++j)
                acc[i][j] = __builtin_amdgcn_mfma_f32_16x16x32_bf16(af[i], bf[j], acc[i][j], 0, 0, 0);
        __syncthreads();
    }

    const int r0 = (lane >> 4) << 2;   // C/D: row=(lane>>4)*4+reg, col=lane&15 (m89-verified)
#pragma unroll
    for (int j = 0; j < 4; ++j) {
        const int col = n0 + wn + j * 16 + fr;
        const float bv = bias[col];
#pragma unroll
        for (int i = 0; i < 4; ++i) {
            const int row = m0 + wm + i * 16 + r0;
#pragma unroll
            for (int r = 0; r < 4; ++r) {
                float v = acc[i][j][r] + bv;
                if (MODE == 1) {
                    v = 0.5f * v * (1.0f + erff(v * 0.70710678118654752f));
                    Cb[(size_t)(row + r) * N + col] = f2bfu(v);
                } else {
                    Cf[(size_t)(row + r) * N + col] = v;
                }
            }
        }
    }
}

// ================= patch embedding as im2col fp32 GEMM + bias + pos_embed =================
__global__ __launch_bounds__(256) void patch_embed_gemm(const float* __restrict__ x,
                                                        const float* __restrict__ W,
                                                        const float* __restrict__ bias,
                                                        const float* __restrict__ pos,
                                                        float* __restrict__ t) {
    __shared__ float Asm[16][68];
    __shared__ float Bsm[16][68];
    const int m0 = (blockIdx.x / 12) * 64;
    const int n0 = (blockIdx.x % 12) * 64;
    const int tid = threadIdx.x;
    const int lr = tid >> 2;
    const int lk = (tid & 3) * 4;
    const int tx = tid & 15, ty = tid >> 4;

    const int m = m0 + lr;
    const int b = m / TT, token = m % TT;
    const int gy = token / GG, gx = token % GG;
    const float* xrow = x + (size_t)b * (3 * IMG * IMG) + (gy * PP) * IMG + gx * PP;

    float acc[4][4] = {};
    for (int kt = 0; kt < 48; ++kt) {
        int c = kt >> 4, py = kt & 15;
        float4 av = *(const float4*)(xrow + ((size_t)c * IMG + py) * IMG + lk);
        float4 bv = *(const float4*)(W + (size_t)(n0 + lr) * DD + kt * 16 + lk);
        __syncthreads();
        Asm[lk + 0][lr] = av.x; Asm[lk + 1][lr] = av.y; Asm[lk + 2][lr] = av.z; Asm[lk + 3][lr] = av.w;
        Bsm[lk + 0][lr] = bv.x; Bsm[lk + 1][lr] = bv.y; Bsm[lk + 2][lr] = bv.z; Bsm[lk + 3][lr] = bv.w;
        __syncthreads();
#pragma unroll
        for (int k = 0; k < 16; ++k) {
            float4 a4 = *(const float4*)&Asm[k][ty * 4];
            float4 b4 = *(const float4*)&Bsm[k][tx * 4];
            float a[4] = {a4.x, a4.y, a4.z, a4.w};
            float b2[4] = {b4.x, b4.y, b4.z, b4.w};
#pragma unroll
            for (int i = 0; i < 4; ++i)
#pragma unroll
                for (int j = 0; j < 4; ++j) acc[i][j] += a[i] * b2[j];
        }
    }
    float4 bi = *(const float4*)(bias + n0 + tx * 4);
#pragma unroll
    for (int i = 0; i < 4; ++i) {
        int mi = m0 + ty * 4 + i;
        int tok = mi % TT;
        float4 p4 = *(const float4*)(pos + (size_t)tok * DD + n0 + tx * 4);
        float4 o;
        o.x = acc[i][0] + bi.x + p4.x;
        o.y = acc[i][1] + bi.y + p4.y;
        o.z = acc[i][2] + bi.z + p4.z;
        o.w = acc[i][3] + bi.w + p4.w;
        *(float4*)(t + (size_t)mi * DD + n0 + tx * 4) = o;
    }
}

// ================= gather visible tokens; write fp32 ctx + bf16 ctx + pad mask =================
__global__ __launch_bounds__(256) void gather_kernel(const float* __restrict__ t,
                                                     const unsigned char* __restrict__ mask8,
                                                     float* __restrict__ ctx,
                                                     unsigned short* __restrict__ ctxb,
                                                     float* __restrict__ pad_out,
                                                     int* __restrict__ lengths, int Sc) {
    __shared__ int s_order[TT];
    __shared__ int s_len;
    const int b = blockIdx.x, tid = threadIdx.x;
    if (tid == 0) {
        const unsigned int* w = (const unsigned int*)mask8;
        int mode = 0;  // 0=int32, 1=uint8, 2=float32
        bool any_f = false, any_big = false;
        for (int i = 0; i < 64; ++i) {
            unsigned int v = w[i];
            if (v == 0x3F800000u) any_f = true;
            else if (v > 1u) any_big = true;
        }
        if (any_f) mode = 2;
        else if (any_big) mode = 1;
        int cnt = 0;
        for (int i = 0; i < TT; ++i) {
            int mv;
            if (mode == 0) mv = mask8[4 * (b * TT + i)];
            else if (mode == 1) mv = mask8[b * TT + i];
            else mv = (w[b * TT + i] != 0u);
            if (mv) s_order[cnt++] = i;
        }
        s_len = cnt;
        lengths[b] = cnt;
    }
    __syncthreads();
    const int len = s_len;
    for (int idx = tid; idx < Sc * DD; idx += 256) {
        int s = idx / DD, d = idx - s * DD;
        float v = 0.f;
        if (s < len) v = t[((size_t)b * TT + s_order[s]) * DD + d];
        ctx[((size_t)b * Sc + s) * DD + d] = v;
        ctxb[((size_t)b * Sc + s) * DD + d] = f2bfu(v);
    }
    for (int s = tid; s < Sc; s += 256) pad_out[b * Sc + s] = (s < len) ? 0.f : 1.f;
}

// ================= attention v3: no-shuffle hot loops =================
// block = (b,h), 512 threads = 8 waves. LDS: pst | qst | Ks | Vs.
// scores: lane=key, K row-natural stride 66 (b64 reads, 2-way bank alias = free),
//         q broadcast from per-wave LDS slot.
// PV: lane=d, p broadcast float4 from per-wave LDS strip, V stride-1.
template <int P>   // P = ceil(Sc/64), Ks has P*64 rows
__global__ __launch_bounds__(512) void attn_v3(const float* __restrict__ qkv,
                                               const int* __restrict__ lengths,
                                               unsigned short* __restrict__ outp, int Sc) {
    extern __shared__ float smem[];
    float* pst = smem;                       // [8][P*64]
    float* qst = pst + 8 * P * 64;           // [8][66]
    float* Ks  = qst + 8 * 66;               // [P*64][66]
    float* Vs  = Ks + P * 64 * 66;           // [Sc][66]
    const int b = blockIdx.x / NH, h = blockIdx.x % NH;
    const int len = lengths[b];
    const int tid = threadIdx.x;
    const float* base = qkv + (size_t)b * Sc * (3 * DD) + h * HD;

    for (int idx = tid; idx < Sc * HD; idx += 512) {
        int s = idx >> 6, d = idx & 63;
        Ks[s * 66 + d] = base[(size_t)s * (3 * DD) + DD + d];
        Vs[s * 66 + d] = base[(size_t)s * (3 * DD) + 2 * DD + d];
    }
    __syncthreads();

    const int wave = tid >> 6, lane = tid & 63;
    float* qw = qst + wave * 66;
    float* pw = pst + wave * P * 64;

    for (int q = wave; q < Sc; q += 8) {
        float qv = base[(size_t)q * (3 * DD) + lane];
        qw[lane] = qv;                      // per-wave slot; compiler orders LDS ops
        float s0 = 0.f, s1 = 0.f, s2 = 0.f, s3 = 0.f;
#pragma unroll
        for (int d0 = 0; d0 < 64; d0 += 2) {
            float2 q2 = *(const float2*)(qw + d0);            // broadcast b64
            float2 k0 = *(const float2*)(Ks + lane * 66 + d0);
            s0 += q2.x * k0.x + q2.y * k0.y;
            if (P > 1) {
                float2 k1 = *(const float2*)(Ks + (lane + 64) * 66 + d0);
                s1 += q2.x * k1.x + q2.y * k1.y;
            }
            if (P > 2) {
                float2 k2 = *(const float2*)(Ks + (lane + 128) * 66 + d0);
                s2 += q2.x * k2.x + q2.y * k2.y;
            }
            if (P > 3) {
                float2 k3 = *(const float2*)(Ks + (lane + 192) * 66 + d0);
                s3 += q2.x * k3.x + q2.y * k3.y;
            }
        }
        s0 = (lane < len) ? s0 * 0.125f : -1e30f;
        if (P > 1) s1 = (64 + lane < len) ? s1 * 0.125f : -1e30f;
        if (P > 2) s2 = (128 + lane < len) ? s2 * 0.125f : -1e30f;
        if (P > 3) s3 = (192 + lane < len) ? s3 * 0.125f : -1e30f;
        float m = s0;
        if (P > 1) m = fmaxf(m, s1);
        if (P > 2) m = fmaxf(m, s2);
        if (P > 3) m = fmaxf(m, s3);
#pragma unroll
        for (int off = 32; off; off >>= 1) m = fmaxf(m, __shfl_xor(m, off, 64));
        s0 = __expf(s0 - m);
        if (P > 1) s1 = __expf(s1 - m);
        if (P > 2) s2 = __expf(s2 - m);
        if (P > 3) s3 = __expf(s3 - m);
        float l = s0;
        if (P > 1) l += s1;
        if (P > 2) l += s2;
        if (P > 3) l += s3;
#pragma unroll
        for (int off = 32; off; off >>= 1) l += __shfl_xor(l, off, 64);
        pw[lane] = s0;
        if (P > 1) pw[64 + lane] = s1;
        if (P > 2) pw[128 + lane] = s2;
        if (P > 3) pw[192 + lane] = s3;
        // PV: lane = d
        float a0 = 0.f, a1 = 0.f, a2 = 0.f, a3 = 0.f;
        const int j4 = len & ~3;
        for (int j = 0; j < j4; j += 4) {
            float4 p4 = *(const float4*)(pw + j);             // broadcast b128
            a0 += p4.x * Vs[(j + 0) * 66 + lane];
            a1 += p4.y * Vs[(j + 1) * 66 + lane];
            a2 += p4.z * Vs[(j + 2) * 66 + lane];
            a3 += p4.w * Vs[(j + 3) * 66 + lane];
        }
        for (int j = j4; j < len; ++j) a0 += pw[j] * Vs[j * 66 + lane];
        float acc = (a0 + a1) + (a2 + a3);
        outp[((size_t)b * Sc + q) * DD + h * HD + lane] = f2bfu(acc / l);
    }
}

// ================= layernorm (+optional residual), fp32 out + optional bf16 out =================
__global__ __launch_bounds__(256) void ln_kernel(const float* __restrict__ x,
                                                 const float* __restrict__ yadd,
                                                 const float* __restrict__ g,
                                                 const float* __restrict__ beta,
                                                 float* __restrict__ outf,
                                                 unsigned short* __restrict__ outb) {
    __shared__ float red[4];
    const size_t row = blockIdx.x;
    const int tid = threadIdx.x;
    float v[3];
#pragma unroll
    for (int i = 0; i < 3; ++i) {
        int d = tid + i * 256;
        float t0 = x[row * DD + d];
        if (yadd) t0 += yadd[row * DD + d];
        v[i] = t0;
    }
    float s = v[0] + v[1] + v[2];
#pragma unroll
    for (int off = 32; off; off >>= 1) s += __shfl_xor(s, off, 64);
    if ((tid & 63) == 0) red[tid >> 6] = s;
    __syncthreads();
    float mean = (red[0] + red[1] + red[2] + red[3]) * (1.0f / 768.0f);
    __syncthreads();
    float vs = 0.f;
#pragma unroll
    for (int i = 0; i < 3; ++i) { float d0 = v[i] - mean; vs += d0 * d0; }
#pragma unroll
    for (int off = 32; off; off >>= 1) vs += __shfl_xor(vs, off, 64);
    if ((tid & 63) == 0) red[tid >> 6] = vs;
    __syncthreads();
    float var = (red[0] + red[1] + red[2] + red[3]) * (1.0f / 768.0f);
    float inv = rsqrtf(var + 1e-5f);
#pragma unroll
    for (int i = 0; i < 3; ++i) {
        int d = tid + i * 256;
        float o = (v[i] - mean) * inv * g[d] + beta[d];
        outf[row * DD + d] = o;
        if (outb) outb[row * DD + d] = f2bfu(o);
    }
}

// ================= fp32 -> bf16 conversion of one layer's 4 weight mats =================
__global__ __launch_bounds__(256) void convert4_bf16(const float* __restrict__ a, int na,
                                                     const float* __restrict__ b, int nb,
                                                     const float* __restrict__ c, int nc,
                                                     const float* __restrict__ d, int nd,
                                                     unsigned short* __restrict__ dst) {
    const int total4 = (na + nb + nc + nd) >> 2;
    for (int u = blockIdx.x * 256 + threadIdx.x; u < total4; u += gridDim.x * 256) {
        int e = u << 2;
        const float* src; int off;
        if (e < na) { src = a; off = e; }
        else if (e < na + nb) { src = b; off = e - na; }
        else if (e < na + nb + nc) { src = c; off = e - na - nb; }
        else { src = d; off = e - na - nb - nc; }
        float4 v = *(const float4*)(src + off);
        ushort4 o;
        o.x = f2bfu(v.x); o.y = f2bfu(v.y); o.z = f2bfu(v.z); o.w = f2bfu(v.w);
        *(ushort4*)(dst + e) = o;
    }
}

extern "C" void kernel_launch(void* const* d_in, const int* in_sizes, int n_in,
                              void* d_out, int out_size, void* d_ws, size_t ws_size,
                              hipStream_t stream) {
    (void)in_sizes; (void)n_in; (void)ws_size;
    const float* x          = (const float*)d_in[0];
    const unsigned char* mk = (const unsigned char*)d_in[1];
    const float* patch_w    = (const float*)d_in[2];
    const float* patch_b    = (const float*)d_in[3];
    const float* pos        = (const float*)d_in[4];
    const float* in_proj_w  = (const float*)d_in[5];
    const float* in_proj_b  = (const float*)d_in[6];
    const float* out_w      = (const float*)d_in[7];
    const float* out_b      = (const float*)d_in[8];
    const float* ln1_g      = (const float*)d_in[9];
    const float* ln1_b      = (const float*)d_in[10];
    const float* ffn_w1     = (const float*)d_in[11];
    const float* ffn_b1     = (const float*)d_in[12];
    const float* ffn_w2     = (const float*)d_in[13];
    const float* ffn_b2     = (const float*)d_in[14];
    const float* ln2_g      = (const float*)d_in[15];
    const float* ln2_b      = (const float*)d_in[16];
    const float* norm_g     = (const float*)d_in[17];
    const float* norm_b     = (const float*)d_in[18];
    float* out = (float*)d_out;

    const int Sc = out_size / (BB * (DD + 1));
    const int M = BB * Sc;
    const int Mp = ((M + 127) / 128) * 128;
    const int MB = Mp / 128;

    // ---- workspace layout ----
    float* t_f   = (float*)d_ws;                          // B*T*D
    float* qkv_f = t_f + (size_t)BB * TT * DD;            // Mp*2304
    float* ctx_f = qkv_f + (size_t)Mp * 2304;             // Mp*768
    float* y_f   = ctx_f + (size_t)Mp * DD;               // Mp*768
    unsigned short* ctx_b  = (unsigned short*)(y_f + (size_t)Mp * DD);  // Mp*768
    unsigned short* attn_b = ctx_b + (size_t)Mp * DD;                    // Mp*768
    unsigned short* h_b    = attn_b + (size_t)Mp * DD;                   // Mp*3072
    unsigned short* wq     = h_b + (size_t)Mp * 4 * DD;                  // 2304*768
    unsigned short* wo     = wq + (size_t)3 * DD * DD;                   // 768*768
    unsigned short* w1     = wo + (size_t)DD * DD;                       // 3072*768
    unsigned short* w2     = w1 + (size_t)4 * DD * DD;                   // 768*3072
    int* lengths = (int*)(w2 + (size_t)4 * DD * DD);

    patch_embed_gemm<<<TT * 12, 256, 0, stream>>>(x, patch_w, patch_b, pos, t_f);
    gather_kernel<<<BB, 256, 0, stream>>>(t_f, mk, ctx_f, ctx_b, out + (size_t)M * DD, lengths, Sc);

    int P = (Sc + 63) / 64; if (P > 4) P = 4;
    size_t smem_attn = (size_t)(8 * P * 64 + 8 * 66 + (size_t)(P * 64 + Sc) * 66) * sizeof(float);
    {
        const void* fp = (P == 1) ? (const void*)attn_v3<1> : (P == 2) ? (const void*)attn_v3<2>
                       : (P == 3) ? (const void*)attn_v3<3> : (const void*)attn_v3<4>;
        (void)hipFuncSetAttribute(fp, hipFuncAttributeMaxDynamicSharedMemorySize, (int)smem_attn);
    }

    for (int l = 0; l < NL; ++l) {
        convert4_bf16<<<1024, 256, 0, stream>>>(
            in_proj_w + (size_t)l * 3 * DD * DD, 3 * DD * DD,
            out_w + (size_t)l * DD * DD, DD * DD,
            ffn_w1 + (size_t)l * 4 * DD * DD, 4 * DD * DD,
            ffn_w2 + (size_t)l * 4 * DD * DD, 4 * DD * DD, wq);
        gemm_mfma<0><<<MB * 18, 256, 0, stream>>>(ctx_b, wq, in_proj_b + (size_t)l * 3 * DD,
                                                  qkv_f, nullptr, Mp, 3 * DD, DD);
        switch (P) {
            case 1: attn_v3<1><<<BB * NH, 512, smem_attn, stream>>>(qkv_f, lengths, attn_b, Sc); break;
            case 2: attn_v3<2><<<BB * NH, 512, smem_attn, stream>>>(qkv_f, lengths, attn_b, Sc); break;
            case 3: attn_v3<3><<<BB * NH, 512, smem_attn, stream>>>(qkv_f, lengths, attn_b, Sc); break;
            default: attn_v3<4><<<BB * NH, 512, smem_attn, stream>>>(qkv_f, lengths, attn_b, Sc); break;
        }
        gemm_mfma<0><<<MB * 6, 256, 0, stream>>>(attn_b, wo, out_b + (size_t)l * DD,
                                                 y_f, nullptr, Mp, DD, DD);
        ln_kernel<<<M, 256, 0, stream>>>(ctx_f, y_f, ln1_g + (size_t)l * DD,
                                         ln1_b + (size_t)l * DD, ctx_f, ctx_b);
        gemm_mfma<1><<<MB * 24, 256, 0, stream>>>(ctx_b, w1, ffn_b1 + (size_t)l * 4 * DD,
                                                  nullptr, h_b, Mp, 4 * DD, DD);
        gemm_mfma<0><<<MB * 6, 256, 0, stream>>>(h_b, w2, ffn_b2 + (size_t)l * DD,
                                                 y_f, nullptr, Mp, DD, 4 * DD);
        ln_kernel<<<M, 256, 0, stream>>>(ctx_f, y_f, ln2_g + (size_t)l * DD,
                                         ln2_b + (size_t)l * DD, ctx_f, ctx_b);
    }
    ln_kernel<<<M, 256, 0, stream>>>(ctx_f, nullptr, norm_g, norm_b, out, nullptr);
}